// Round 6
// baseline (77.818 us; speedup 1.0000x reference)
//
#include <hip/hip_runtime.h>
#include <hip/hip_bf16.h>
#include <math.h>

#define BB 4
#define CCH 128     // channels
#define HH 64
#define WW 256
#define RR 8
#define KWIN 17
#define TW 32       // output w-tile per block
#define TWH 48      // TW + 2R (halo)
#define NTHREADS 256
#define PIT 136     // pitch (shorts) for [row][c] bf16 arrays (row stride 68 dw = 4 mod 32)
#define STP 36      // St pitch (floats)
#define PTP 72      // Pt pitch (shorts)

typedef __attribute__((ext_vector_type(8))) short short8;
typedef __attribute__((ext_vector_type(4))) short short4v;
typedef __attribute__((ext_vector_type(4))) float f32x4;

__device__ __forceinline__ short f2bf(float x) {
    union { __hip_bfloat16 b; short s; } u;
    u.b = __float2bfloat16(x);
    return u.s;
}

__global__ __launch_bounds__(NTHREADS, 4)
void attn1d_fused(const float* __restrict__ feature,
                  const float* __restrict__ position,
                  const float* __restrict__ Wq, const float* __restrict__ bq,
                  const float* __restrict__ Wk, const float* __restrict__ bk,
                  float* __restrict__ out)
{
    // Union region (13056 B): fBt lives Phase A->B; St (0..6911) lives C->softmax;
    // Pt (6912..11519) zeroed by wave 3 during C, written softmax, read D.
    __shared__ __align__(16) char uSm[TWH * PIT * 2];
    __shared__ __align__(16) short kT [TWH][PIT];   // 13056 B  k^T [wl][c]
    __shared__ __align__(16) short qT [TW ][PIT];   //  8704 B  q^T [w][c]
                                                    // total 34816 B -> 4 blocks/CU
    short (*fBt)[PIT] = (short(*)[PIT])uSm;         // f^T [wl][c]
    float (*St)[STP]  = (float(*)[STP])uSm;         // S^T [wl'][w]
    short (*Pt)[PTP]  = (short(*)[PTP])(uSm + TWH * STP * 4);  // P [w][wl]

    const int t    = threadIdx.x;
    const int wid  = t >> 6;
    const int lane = t & 63;
    const int lrow = lane & 15;
    const int lgrp = lane >> 4;

    // XCD-chunked bijective swizzle (2048 % 8 == 0)
    int blk = blockIdx.x;
    blk = (blk & 7) * 256 + (blk >> 3);
    const int wt = blk & 7;
    const int bh = blk >> 3;
    const int h  = bh & (HH - 1);
    const int b  = bh >> 6;
    const int w0 = wt * TW - RR;
    const int base = ((b * CCH) * HH + h) * WW;

    // ---- A-fragments: rows of Wq (waves 0,1) / Wk (waves 2,3), bf16 in regs --
    const int   mrow = (wid & 1) * 64;
    const float* Wmat = (wid < 2) ? Wq : Wk;
    const float* bvec = (wid < 2) ? bq : bk;

    short8 afrag[4][4];   // [mf][kk]
    #pragma unroll
    for (int mf = 0; mf < 4; ++mf) {
        const float* wrow = Wmat + (mrow + mf * 16 + lrow) * CCH;
        #pragma unroll
        for (int kk = 0; kk < 4; ++kk) {
            const float* p = wrow + kk * 32 + lgrp * 8;
            const float4 a0 = *(const float4*)p;
            const float4 a1 = *(const float4*)(p + 4);
            short8 s;
            s[0] = f2bf(a0.x); s[1] = f2bf(a0.y); s[2] = f2bf(a0.z); s[3] = f2bf(a0.w);
            s[4] = f2bf(a1.x); s[5] = f2bf(a1.y); s[6] = f2bf(a1.z); s[7] = f2bf(a1.w);
            afrag[mf][kk] = s;
        }
    }
    float bias_r[4][4];
    #pragma unroll
    for (int mf = 0; mf < 4; ++mf)
        #pragma unroll
        for (int reg = 0; reg < 4; ++reg)
            bias_r[mf][reg] = bvec[mrow + mf * 16 + lgrp * 4 + reg];

    // ---------------- Phase A: stage f as fBt (transposed bf16) --------------
    #pragma unroll
    for (int i = 0; i < 6; ++i) {
        const int idx = i * NTHREADS + t;        // 1536 quads
        const int c  = idx / 12;
        const int wq = idx - c * 12;
        const int w  = w0 + wq * 4;              // quad fully in or out (w0 % 4 == 0)
        float4 fv = {0.f, 0.f, 0.f, 0.f};
        if (w >= 0 && w < WW) {
            const int off = base + c * (HH * WW) + w;
            const float4 fa = *(const float4*)(feature + off);
            const float4 pa = *(const float4*)(position + off);
            fv.x = fa.x + pa.x; fv.y = fa.y + pa.y;
            fv.z = fa.z + pa.z; fv.w = fa.w + pa.w;
        }
        fBt[wq * 4 + 0][c] = f2bf(fv.x);
        fBt[wq * 4 + 1][c] = f2bf(fv.y);
        fBt[wq * 4 + 2][c] = f2bf(fv.z);
        fBt[wq * 4 + 3][c] = f2bf(fv.w);
    }
    __syncthreads();

    // ---------------- Phase B: q,k = [Wq;Wk] f + bias via MFMA ----------------
    f32x4 acc[4][3];
    #pragma unroll
    for (int mf = 0; mf < 4; ++mf)
        #pragma unroll
        for (int nf = 0; nf < 3; ++nf)
            acc[mf][nf] = (f32x4){0.f, 0.f, 0.f, 0.f};

    #pragma unroll
    for (int kk = 0; kk < 4; ++kk) {
        short8 bfr[3];
        #pragma unroll
        for (int nf = 0; nf < 3; ++nf)
            bfr[nf] = *(const short8*)&fBt[nf * 16 + lrow][kk * 32 + lgrp * 8];
        #pragma unroll
        for (int mf = 0; mf < 4; ++mf)
            #pragma unroll
            for (int nf = 0; nf < 3; ++nf)
                acc[mf][nf] = __builtin_amdgcn_mfma_f32_16x16x32_bf16(
                    afrag[mf][kk], bfr[nf], acc[mf][nf], 0, 0, 0);
    }

    // writeback transposed bf16: q -> qT (w rows 8..39), k -> kT (all, zero OOB)
    if (wid < 2) {
        #pragma unroll
        for (int mf = 0; mf < 4; ++mf)
            #pragma unroll
            for (int nf = 0; nf < 3; ++nf) {
                const int wl = nf * 16 + lrow;
                if (wl >= RR && wl < RR + TW) {
                    short4v s;
                    #pragma unroll
                    for (int reg = 0; reg < 4; ++reg)
                        s[reg] = f2bf(acc[mf][nf][reg] + bias_r[mf][reg]);
                    *(short4v*)&qT[wl - RR][mrow + mf * 16 + lgrp * 4] = s;
                }
            }
    } else {
        #pragma unroll
        for (int mf = 0; mf < 4; ++mf)
            #pragma unroll
            for (int nf = 0; nf < 3; ++nf) {
                const int wl = nf * 16 + lrow;
                const int w  = w0 + wl;
                const bool inb = (w >= 0 && w < WW);
                short4v s;
                #pragma unroll
                for (int reg = 0; reg < 4; ++reg)
                    s[reg] = inb ? f2bf(acc[mf][nf][reg] + bias_r[mf][reg]) : (short)0;
                *(short4v*)&kT[wl][mrow + mf * 16 + lgrp * 4] = s;
            }
    }
    __syncthreads();   // fBt dead from here -> St/Pt may use its space

    // ---------------- Phase C: S^T = (q^T k) / sqrt(C) via MFMA ---------------
    if (wid < 3) {
        const int nf = wid;          // wl' block 0..2
        f32x4 s0 = {0.f,0.f,0.f,0.f}, s1 = {0.f,0.f,0.f,0.f};
        #pragma unroll
        for (int kk = 0; kk < 4; ++kk) {
            const short8 a0 = *(const short8*)&qT[lrow     ][kk * 32 + lgrp * 8];
            const short8 a1 = *(const short8*)&qT[16 + lrow][kk * 32 + lgrp * 8];
            const short8 bb = *(const short8*)&kT[nf * 16 + lrow][kk * 32 + lgrp * 8];
            s0 = __builtin_amdgcn_mfma_f32_16x16x32_bf16(a0, bb, s0, 0, 0, 0);
            s1 = __builtin_amdgcn_mfma_f32_16x16x32_bf16(a1, bb, s1, 0, 0, 0);
        }
        const float isc = 0.08838834764831845f;   // 1/sqrt(128)
        *(f32x4*)&St[nf * 16 + lrow][lgrp * 4]      = s0 * isc;
        *(f32x4*)&St[nf * 16 + lrow][16 + lgrp * 4] = s1 * isc;
    } else {
        // wave 3: zero-fill Pt (32 x 72 shorts = 288 short8 chunks)
        const short8 z = {0,0,0,0,0,0,0,0};
        short* p = &Pt[0][0];
        for (int i = lane; i < (TW * PTP) / 8; i += 64)
            *(short8*)(p + i * 8) = z;
    }
    __syncthreads();

    // ---------------- softmax over 17 taps (parallel: 4 threads/row) ---------
    if (t < TW * 4) {
        const int w = t >> 2, g = t & 3;
        const int nt = (g == 0) ? 5 : 4;          // taps j = g + 4i, plus j=16 for g==0
        float sv[5];
        float mx = -3.0e38f;
        #pragma unroll
        for (int i = 0; i < 5; ++i) {
            if (i < nt) {
                const int j = (i == 4) ? 16 : (g + i * 4);
                sv[i] = St[w + j][w];
                mx = fmaxf(mx, sv[i]);
            }
        }
        mx = fmaxf(mx, __shfl_xor(mx, 1, 4));
        mx = fmaxf(mx, __shfl_xor(mx, 2, 4));
        float sum = 0.f;
        #pragma unroll
        for (int i = 0; i < 5; ++i)
            if (i < nt) { sv[i] = __expf(sv[i] - mx); sum += sv[i]; }
        sum += __shfl_xor(sum, 1, 4);
        sum += __shfl_xor(sum, 2, 4);
        const float inv = 1.f / sum;
        #pragma unroll
        for (int i = 0; i < 5; ++i)
            if (i < nt) {
                const int j = (i == 4) ? 16 : (g + i * 4);
                Pt[w][w + j] = f2bf(sv[i] * inv);
            }
    }
    __syncthreads();

    // ---------------- Phase D: out = f . P^T via MFMA -------------------------
    // A-frags re-loaded from global (L2-hot): f[c][wl], wl = kk*32+lgrp*8+{0..7}.
    // 8-runs are always fully in or fully out of [0,WW); out/padded runs -> 0
    // (Pt cols >=48 are also zero, so the kk=1,lgrp>=2 pads are doubly safe).
    {
        const int cb = wid * 32;
        const int cA0 = cb + lrow;
        const int cA1 = cb + 16 + lrow;
        short8 afD[2][2];   // [c-half][kk]
        #pragma unroll
        for (int ch = 0; ch < 2; ++ch) {
            const int c = (ch == 0) ? cA0 : cA1;
            #pragma unroll
            for (int kk = 0; kk < 2; ++kk) {
                const int wl_b = kk * 32 + lgrp * 8;
                const int w    = w0 + wl_b;
                short8 s = {0,0,0,0,0,0,0,0};
                if (wl_b < TWH && w >= 0 && w <= WW - 8) {
                    const int off = base + c * (HH * WW) + w;
                    const float4 fa0 = *(const float4*)(feature + off);
                    const float4 fa1 = *(const float4*)(feature + off + 4);
                    const float4 pa0 = *(const float4*)(position + off);
                    const float4 pa1 = *(const float4*)(position + off + 4);
                    s[0] = f2bf(fa0.x + pa0.x); s[1] = f2bf(fa0.y + pa0.y);
                    s[2] = f2bf(fa0.z + pa0.z); s[3] = f2bf(fa0.w + pa0.w);
                    s[4] = f2bf(fa1.x + pa1.x); s[5] = f2bf(fa1.y + pa1.y);
                    s[6] = f2bf(fa1.z + pa1.z); s[7] = f2bf(fa1.w + pa1.w);
                }
                afD[ch][kk] = s;
            }
        }

        f32x4 d00 = {0.f,0.f,0.f,0.f}, d01 = d00, d10 = d00, d11 = d00;
        #pragma unroll
        for (int kk = 0; kk < 2; ++kk) {
            const short8 b0 = *(const short8*)&Pt[lrow     ][kk * 32 + lgrp * 8];
            const short8 b1 = *(const short8*)&Pt[16 + lrow][kk * 32 + lgrp * 8];
            d00 = __builtin_amdgcn_mfma_f32_16x16x32_bf16(afD[0][kk], b0, d00, 0, 0, 0);
            d01 = __builtin_amdgcn_mfma_f32_16x16x32_bf16(afD[0][kk], b1, d01, 0, 0, 0);
            d10 = __builtin_amdgcn_mfma_f32_16x16x32_bf16(afD[1][kk], b0, d10, 0, 0, 0);
            d11 = __builtin_amdgcn_mfma_f32_16x16x32_bf16(afD[1][kk], b1, d11, 0, 0, 0);
        }
        const int wbase = wt * TW;
        #pragma unroll
        for (int reg = 0; reg < 4; ++reg) {
            const int c0 = cb + lgrp * 4 + reg;
            out[base + c0 * (HH * WW)        + wbase + lrow]      = d00[reg];
            out[base + c0 * (HH * WW)        + wbase + 16 + lrow] = d01[reg];
            out[base + (c0 + 16) * (HH * WW) + wbase + lrow]      = d10[reg];
            out[base + (c0 + 16) * (HH * WW) + wbase + 16 + lrow] = d11[reg];
        }
    }
}

extern "C" void kernel_launch(void* const* d_in, const int* in_sizes, int n_in,
                              void* d_out, int out_size, void* d_ws, size_t ws_size,
                              hipStream_t stream) {
    const float* feature  = (const float*)d_in[0];
    const float* position = (const float*)d_in[1];
    const float* Wq = (const float*)d_in[2];
    const float* bq = (const float*)d_in[3];
    const float* Wk = (const float*)d_in[4];
    const float* bk = (const float*)d_in[5];
    float* out = (float*)d_out;

    const dim3 grid(BB * HH * (WW / TW));   // 2048 blocks
    attn1d_fused<<<grid, NTHREADS, 0, stream>>>(feature, position, Wq, bq, Wk, bk, out);
}

// Round 7
// 70.701 us; speedup vs baseline: 1.1007x; 1.1007x over previous
//
#include <hip/hip_runtime.h>
#include <hip/hip_bf16.h>
#include <math.h>

#define BB 4
#define CCH 128     // channels
#define HH 64
#define WW 256
#define RR 8
#define KWIN 17
#define TW 32       // output w-tile per block
#define TWH 48      // TW + 2R (halo)
#define NTHREADS 256
#define HPB 2       // h-rows per block (software-pipelined)
#define PIT 136     // pitch (shorts) for [row][c] bf16 arrays (row stride 68 dw = 4 mod 32)
#define FAP 72      // fA pitch (shorts)
#define STP 36      // St pitch (floats)
#define PTP 72      // Pt pitch (shorts)

typedef __attribute__((ext_vector_type(8))) short short8;
typedef __attribute__((ext_vector_type(4))) short short4v;
typedef __attribute__((ext_vector_type(4))) float f32x4;

__device__ __forceinline__ short f2bf(float x) {
    union { __hip_bfloat16 b; short s; } u;
    u.b = __float2bfloat16(x);
    return u.s;
}

__global__ __launch_bounds__(NTHREADS, 3)
void attn1d_fused(const float* __restrict__ feature,
                  const float* __restrict__ position,
                  const float* __restrict__ Wq, const float* __restrict__ bq,
                  const float* __restrict__ Wk, const float* __restrict__ bk,
                  float* __restrict__ out)
{
    // Union region (13056 B): per iteration, fBt lives top->B; St (0..6911) C->softmax;
    // Pt (6912..11519) zeroed by wave 3 during C, written softmax, read D.
    // End-of-iteration barrier protects fBt rewrite vs prev St/Pt readers.
    __shared__ __align__(16) char uSm[TWH * PIT * 2];
    __shared__ __align__(16) short kT [TWH][PIT];   // 13056 B  k^T [wl][c]
    __shared__ __align__(16) short qT [TW ][PIT];   //  8704 B  q^T [w][c]
    __shared__ __align__(16) short fA [CCH][FAP];   // 18432 B  f [c][wl] (cols 48..63 zero)
                                                    // total 53248 B -> 3 blocks/CU
    short (*fBt)[PIT] = (short(*)[PIT])uSm;         // f^T [wl][c]
    float (*St)[STP]  = (float(*)[STP])uSm;         // S^T [wl'][w]
    short (*Pt)[PTP]  = (short(*)[PTP])(uSm + TWH * STP * 4);  // P [w][wl]

    const int t    = threadIdx.x;
    const int wid  = t >> 6;
    const int lane = t & 63;
    const int lrow = lane & 15;
    const int lgrp = lane >> 4;

    // XCD-chunked bijective swizzle (1024 % 8 == 0)
    int blk = blockIdx.x;
    blk = (blk & 7) * 128 + (blk >> 3);
    const int wt   = blk & 7;
    const int rest = blk >> 3;           // 0..127
    const int hh   = rest & 31;
    const int b    = rest >> 5;
    const int w0   = wt * TW - RR;
    const int h0   = hh * HPB;

    // staging decomposition (constant per thread across iterations)
    // idx = i*256 + t ; c = idx/12 ; wq = idx%12
    int s_c[6], s_wq[6];
    #pragma unroll
    for (int i = 0; i < 6; ++i) {
        const int idx = i * NTHREADS + t;
        s_c[i]  = idx / 12;
        s_wq[i] = idx - s_c[i] * 12;
    }

    // ---- A-fragments: rows of Wq (waves 0,1) / Wk (waves 2,3), bf16 in regs --
    const int   mrow = (wid & 1) * 64;
    const float* Wmat = (wid < 2) ? Wq : Wk;
    const float* bvec = (wid < 2) ? bq : bk;

    short8 afrag[4][4];   // [mf][kk]
    #pragma unroll
    for (int mf = 0; mf < 4; ++mf) {
        const float* wrow = Wmat + (mrow + mf * 16 + lrow) * CCH;
        #pragma unroll
        for (int kk = 0; kk < 4; ++kk) {
            const float* p = wrow + kk * 32 + lgrp * 8;
            const float4 a0 = *(const float4*)p;
            const float4 a1 = *(const float4*)(p + 4);
            short8 s;
            s[0] = f2bf(a0.x); s[1] = f2bf(a0.y); s[2] = f2bf(a0.z); s[3] = f2bf(a0.w);
            s[4] = f2bf(a1.x); s[5] = f2bf(a1.y); s[6] = f2bf(a1.z); s[7] = f2bf(a1.w);
            afrag[mf][kk] = s;
        }
    }
    float bias_r[4][4];
    #pragma unroll
    for (int mf = 0; mf < 4; ++mf)
        #pragma unroll
        for (int reg = 0; reg < 4; ++reg)
            bias_r[mf][reg] = bvec[mrow + mf * 16 + lgrp * 4 + reg];

    // zero fA k-pad cols 48..63 (once; never overwritten)
    {
        const short8 z = {0,0,0,0,0,0,0,0};
        const int zc = t >> 1, zs = t & 1;
        *(short8*)&fA[zc][48 + zs * 8] = z;
    }

    // ---- prefetch tile 0: f = feature + position -> registers (bf16 quads) --
    short4v s4pf[6];
    {
        const int base0 = ((b * CCH) * HH + h0) * WW;
        #pragma unroll
        for (int i = 0; i < 6; ++i) {
            const int w = w0 + s_wq[i] * 4;
            float4 fv = {0.f, 0.f, 0.f, 0.f};
            if (w >= 0 && w < WW) {
                const int off = base0 + s_c[i] * (HH * WW) + w;
                const float4 fa = *(const float4*)(feature + off);
                const float4 pa = *(const float4*)(position + off);
                fv.x = fa.x + pa.x; fv.y = fa.y + pa.y;
                fv.z = fa.z + pa.z; fv.w = fa.w + pa.w;
            }
            short4v s4;
            s4[0] = f2bf(fv.x); s4[1] = f2bf(fv.y); s4[2] = f2bf(fv.z); s4[3] = f2bf(fv.w);
            s4pf[i] = s4;
        }
    }

    for (int it = 0; it < HPB; ++it) {
        const int h    = h0 + it;
        const int base = ((b * CCH) * HH + h) * WW;

        // ---------------- loop top: registers -> fBt + fA ---------------------
        #pragma unroll
        for (int i = 0; i < 6; ++i) {
            const int c = s_c[i], wq = s_wq[i];
            const short4v s4 = s4pf[i];
            *(short4v*)&fA[c][wq * 4] = s4;
            fBt[wq * 4 + 0][c] = s4[0];
            fBt[wq * 4 + 1][c] = s4[1];
            fBt[wq * 4 + 2][c] = s4[2];
            fBt[wq * 4 + 3][c] = s4[3];
        }
        __syncthreads();

        // ---------------- Phase B: q,k = [Wq;Wk] f + bias via MFMA ------------
        f32x4 acc[4][3];
        #pragma unroll
        for (int mf = 0; mf < 4; ++mf)
            #pragma unroll
            for (int nf = 0; nf < 3; ++nf)
                acc[mf][nf] = (f32x4){0.f, 0.f, 0.f, 0.f};

        #pragma unroll
        for (int kk = 0; kk < 4; ++kk) {
            short8 bfr[3];
            #pragma unroll
            for (int nf = 0; nf < 3; ++nf)
                bfr[nf] = *(const short8*)&fBt[nf * 16 + lrow][kk * 32 + lgrp * 8];
            #pragma unroll
            for (int mf = 0; mf < 4; ++mf)
                #pragma unroll
                for (int nf = 0; nf < 3; ++nf)
                    acc[mf][nf] = __builtin_amdgcn_mfma_f32_16x16x32_bf16(
                        afrag[mf][kk], bfr[nf], acc[mf][nf], 0, 0, 0);
        }

        // ---- prefetch next tile's f into registers (hidden under C/D) --------
        if (it + 1 < HPB) {
            const int basen = base + WW;    // h+1
            #pragma unroll
            for (int i = 0; i < 6; ++i) {
                const int w = w0 + s_wq[i] * 4;
                float4 fv = {0.f, 0.f, 0.f, 0.f};
                if (w >= 0 && w < WW) {
                    const int off = basen + s_c[i] * (HH * WW) + w;
                    const float4 fa = *(const float4*)(feature + off);
                    const float4 pa = *(const float4*)(position + off);
                    fv.x = fa.x + pa.x; fv.y = fa.y + pa.y;
                    fv.z = fa.z + pa.z; fv.w = fa.w + pa.w;
                }
                short4v s4;
                s4[0] = f2bf(fv.x); s4[1] = f2bf(fv.y); s4[2] = f2bf(fv.z); s4[3] = f2bf(fv.w);
                s4pf[i] = s4;
            }
        }

        // writeback transposed bf16: q -> qT (w rows 8..39), k -> kT (zero OOB)
        if (wid < 2) {
            #pragma unroll
            for (int mf = 0; mf < 4; ++mf)
                #pragma unroll
                for (int nf = 0; nf < 3; ++nf) {
                    const int wl = nf * 16 + lrow;
                    if (wl >= RR && wl < RR + TW) {
                        short4v s;
                        #pragma unroll
                        for (int reg = 0; reg < 4; ++reg)
                            s[reg] = f2bf(acc[mf][nf][reg] + bias_r[mf][reg]);
                        *(short4v*)&qT[wl - RR][mrow + mf * 16 + lgrp * 4] = s;
                    }
                }
        } else {
            #pragma unroll
            for (int mf = 0; mf < 4; ++mf)
                #pragma unroll
                for (int nf = 0; nf < 3; ++nf) {
                    const int wl = nf * 16 + lrow;
                    const int w  = w0 + wl;
                    const bool inb = (w >= 0 && w < WW);
                    short4v s;
                    #pragma unroll
                    for (int reg = 0; reg < 4; ++reg)
                        s[reg] = inb ? f2bf(acc[mf][nf][reg] + bias_r[mf][reg]) : (short)0;
                    *(short4v*)&kT[wl][mrow + mf * 16 + lgrp * 4] = s;
                }
        }
        __syncthreads();   // fBt dead -> St/Pt may use its space

        // ---------------- Phase C: S^T = (q^T k) / sqrt(C) via MFMA -----------
        if (wid < 3) {
            const int nf = wid;          // wl' block 0..2
            f32x4 s0 = {0.f,0.f,0.f,0.f}, s1 = {0.f,0.f,0.f,0.f};
            #pragma unroll
            for (int kk = 0; kk < 4; ++kk) {
                const short8 a0 = *(const short8*)&qT[lrow     ][kk * 32 + lgrp * 8];
                const short8 a1 = *(const short8*)&qT[16 + lrow][kk * 32 + lgrp * 8];
                const short8 bb = *(const short8*)&kT[nf * 16 + lrow][kk * 32 + lgrp * 8];
                s0 = __builtin_amdgcn_mfma_f32_16x16x32_bf16(a0, bb, s0, 0, 0, 0);
                s1 = __builtin_amdgcn_mfma_f32_16x16x32_bf16(a1, bb, s1, 0, 0, 0);
            }
            const float isc = 0.08838834764831845f;   // 1/sqrt(128)
            *(f32x4*)&St[nf * 16 + lrow][lgrp * 4]      = s0 * isc;
            *(f32x4*)&St[nf * 16 + lrow][16 + lgrp * 4] = s1 * isc;
        } else {
            // wave 3: zero-fill Pt (32 x 72 shorts = 288 short8 chunks)
            const short8 z = {0,0,0,0,0,0,0,0};
            short* p = &Pt[0][0];
            for (int i = lane; i < (TW * PTP) / 8; i += 64)
                *(short8*)(p + i * 8) = z;
        }
        __syncthreads();

        // ---------------- softmax over 17 taps (4 threads/row) ----------------
        if (t < TW * 4) {
            const int w = t >> 2, g = t & 3;
            const int nt = (g == 0) ? 5 : 4;      // taps j = g + 4i, plus j=16 for g==0
            float sv[5];
            float mx = -3.0e38f;
            #pragma unroll
            for (int i = 0; i < 5; ++i) {
                if (i < nt) {
                    const int j = (i == 4) ? 16 : (g + i * 4);
                    sv[i] = St[w + j][w];
                    mx = fmaxf(mx, sv[i]);
                }
            }
            mx = fmaxf(mx, __shfl_xor(mx, 1, 4));
            mx = fmaxf(mx, __shfl_xor(mx, 2, 4));
            float sum = 0.f;
            #pragma unroll
            for (int i = 0; i < 5; ++i)
                if (i < nt) { sv[i] = __expf(sv[i] - mx); sum += sv[i]; }
            sum += __shfl_xor(sum, 1, 4);
            sum += __shfl_xor(sum, 2, 4);
            const float inv = 1.f / sum;
            #pragma unroll
            for (int i = 0; i < 5; ++i)
                if (i < nt) {
                    const int j = (i == 4) ? 16 : (g + i * 4);
                    Pt[w][w + j] = f2bf(sv[i] * inv);
                }
        }
        __syncthreads();

        // ---------------- Phase D: out = f . P^T via MFMA ---------------------
        {
            const int cb = wid * 32;
            f32x4 d00 = {0.f,0.f,0.f,0.f}, d01 = d00, d10 = d00, d11 = d00;
            #pragma unroll
            for (int kk = 0; kk < 2; ++kk) {
                const short8 a0 = *(const short8*)&fA[cb + lrow     ][kk * 32 + lgrp * 8];
                const short8 a1 = *(const short8*)&fA[cb + 16 + lrow][kk * 32 + lgrp * 8];
                const short8 b0 = *(const short8*)&Pt[lrow     ][kk * 32 + lgrp * 8];
                const short8 b1 = *(const short8*)&Pt[16 + lrow][kk * 32 + lgrp * 8];
                d00 = __builtin_amdgcn_mfma_f32_16x16x32_bf16(a0, b0, d00, 0, 0, 0);
                d01 = __builtin_amdgcn_mfma_f32_16x16x32_bf16(a0, b1, d01, 0, 0, 0);
                d10 = __builtin_amdgcn_mfma_f32_16x16x32_bf16(a1, b0, d10, 0, 0, 0);
                d11 = __builtin_amdgcn_mfma_f32_16x16x32_bf16(a1, b1, d11, 0, 0, 0);
            }
            const int wbase = wt * TW;
            #pragma unroll
            for (int reg = 0; reg < 4; ++reg) {
                const int c0 = cb + lgrp * 4 + reg;
                out[base + c0 * (HH * WW)        + wbase + lrow]      = d00[reg];
                out[base + c0 * (HH * WW)        + wbase + 16 + lrow] = d01[reg];
                out[base + (c0 + 16) * (HH * WW) + wbase + lrow]      = d10[reg];
                out[base + (c0 + 16) * (HH * WW) + wbase + 16 + lrow] = d11[reg];
            }
        }
        __syncthreads();   // protect fBt rewrite (next it) vs St/Pt readers
    }
}

extern "C" void kernel_launch(void* const* d_in, const int* in_sizes, int n_in,
                              void* d_out, int out_size, void* d_ws, size_t ws_size,
                              hipStream_t stream) {
    const float* feature  = (const float*)d_in[0];
    const float* position = (const float*)d_in[1];
    const float* Wq = (const float*)d_in[2];
    const float* bq = (const float*)d_in[3];
    const float* Wk = (const float*)d_in[4];
    const float* bk = (const float*)d_in[5];
    float* out = (float*)d_out;

    const dim3 grid(BB * HH * (WW / TW) / HPB);   // 1024 blocks
    attn1d_fused<<<grid, NTHREADS, 0, stream>>>(feature, position, Wq, bq, Wk, bk, out);
}

// Round 8
// 61.194 us; speedup vs baseline: 1.2717x; 1.1554x over previous
//
#include <hip/hip_runtime.h>
#include <hip/hip_bf16.h>
#include <math.h>

#define BB 4
#define CCH 128     // channels
#define HH 64
#define WW 256
#define RR 8
#define KWIN 17
#define TW 32       // output w-tile per block
#define TWH 48      // TW + 2R (halo)
#define NTHREADS 256
#define PIT 136     // pitch (shorts) for [row][c] bf16 arrays (row stride 68 dw = 4 mod 32)
#define FAP 72      // fA pitch (shorts)
#define STP 36      // St pitch (floats)
#define PTP 72      // Pt pitch (shorts)

typedef __attribute__((ext_vector_type(8))) short short8;
typedef __attribute__((ext_vector_type(4))) short short4v;
typedef __attribute__((ext_vector_type(4))) float f32x4;

__device__ __forceinline__ short f2bf(float x) {
    union { __hip_bfloat16 b; short s; } u;
    u.b = __float2bfloat16(x);
    return u.s;
}

// fBt physical column layout: phys col 2p holds logical c=p, phys col 2p+1 holds
// logical c=p+64. Phase B's A-fragments gather W columns in the SAME interleaved
// order, so the MFMA k-reduction is consistent (k-permutation invariant).

__global__ __launch_bounds__(NTHREADS, 3)
void attn1d_fused(const float* __restrict__ feature,
                  const float* __restrict__ position,
                  const float* __restrict__ Wq, const float* __restrict__ bq,
                  const float* __restrict__ Wk, const float* __restrict__ bk,
                  float* __restrict__ out)
{
    // Union region (13056 B): fBt lives Phase A->B; St (0..6911) lives C->softmax;
    // Pt (6912..11519) zeroed by wave 3 during C, written softmax, read D.
    __shared__ __align__(16) char uSm[TWH * PIT * 2];
    __shared__ __align__(16) short kT [TWH][PIT];   // 13056 B  k^T [wl][c]
    __shared__ __align__(16) short qT [TW ][PIT];   //  8704 B  q^T [w][c]
    __shared__ __align__(16) short fA [CCH][FAP];   // 18432 B  f [c][wl] (cols 48..63 zero)
                                                    // total 53248 B -> 3 blocks/CU
    short (*fBt)[PIT] = (short(*)[PIT])uSm;         // f^T [wl][phys col]
    float (*St)[STP]  = (float(*)[STP])uSm;         // S^T [wl'][w]
    short (*Pt)[PTP]  = (short(*)[PTP])(uSm + TWH * STP * 4);  // P [w][wl]

    const int t    = threadIdx.x;
    const int wid  = t >> 6;
    const int lane = t & 63;
    const int lrow = lane & 15;
    const int lgrp = lane >> 4;

    // XCD-chunked bijective swizzle (2048 % 8 == 0)
    int blk = blockIdx.x;
    blk = (blk & 7) * 256 + (blk >> 3);
    const int wt = blk & 7;
    const int bh = blk >> 3;
    const int h  = bh & (HH - 1);
    const int b  = bh >> 6;
    const int w0 = wt * TW - RR;
    const int base = ((b * CCH) * HH + h) * WW;

    // ---------------- Phase A loads issued FIRST (hide under W setup) --------
    // unit i: thread handles c rows {lane, lane+64} x w-quad wq = i*4+wid
    f32x4 fL[3][4];            // [i][{f_c, f_c64, p_c, p_c64}]
    #pragma unroll
    for (int i = 0; i < 3; ++i) {
        const int wq = i * 4 + wid;
        const int w  = w0 + wq * 4;          // quad fully in or out (w0 % 4 == 0)
        const f32x4 z4 = {0.f, 0.f, 0.f, 0.f};
        fL[i][0] = z4; fL[i][1] = z4; fL[i][2] = z4; fL[i][3] = z4;
        if (w >= 0 && w < WW) {
            const int off = base + lane * (HH * WW) + w;
            fL[i][0] = *(const f32x4*)(feature  + off);
            fL[i][1] = *(const f32x4*)(feature  + off + 64 * HH * WW);
            fL[i][2] = *(const f32x4*)(position + off);
            fL[i][3] = *(const f32x4*)(position + off + 64 * HH * WW);
        }
    }

    // ---- A-fragments: rows of Wq (waves 0,1) / Wk (waves 2,3), bf16 in regs --
    // k-gather uses the interleaved column order matching fBt's physical layout:
    // s[2m] = col (kk*16 + lgrp*4 + m), s[2m+1] = col (64 + kk*16 + lgrp*4 + m)
    const int   mrow = (wid & 1) * 64;
    const float* Wmat = (wid < 2) ? Wq : Wk;
    const float* bvec = (wid < 2) ? bq : bk;

    short8 afrag[4][4];   // [mf][kk]
    #pragma unroll
    for (int mf = 0; mf < 4; ++mf) {
        const float* wrow = Wmat + (mrow + mf * 16 + lrow) * CCH;
        #pragma unroll
        for (int kk = 0; kk < 4; ++kk) {
            const float* p = wrow + kk * 16 + lgrp * 4;
            const f32x4 a0 = *(const f32x4*)p;
            const f32x4 a1 = *(const f32x4*)(p + 64);
            short8 s;
            s[0] = f2bf(a0[0]); s[1] = f2bf(a1[0]);
            s[2] = f2bf(a0[1]); s[3] = f2bf(a1[1]);
            s[4] = f2bf(a0[2]); s[5] = f2bf(a1[2]);
            s[6] = f2bf(a0[3]); s[7] = f2bf(a1[3]);
            afrag[mf][kk] = s;
        }
    }
    float bias_r[4][4];
    #pragma unroll
    for (int mf = 0; mf < 4; ++mf)
        #pragma unroll
        for (int reg = 0; reg < 4; ++reg)
            bias_r[mf][reg] = bvec[mrow + mf * 16 + lgrp * 4 + reg];

    // zero fA k-pad cols 48..63
    {
        const short8 z = {0,0,0,0,0,0,0,0};
        const int zc = t >> 1, zs = t & 1;
        *(short8*)&fA[zc][48 + zs * 8] = z;
    }

    // ---------------- Phase A writes: fBt (packed u32, conflict-free) + fA ---
    #pragma unroll
    for (int i = 0; i < 3; ++i) {
        const int wq = i * 4 + wid;
        short4v s0, s1;
        #pragma unroll
        for (int j = 0; j < 4; ++j) {
            s0[j] = f2bf(fL[i][0][j] + fL[i][2][j]);   // c = lane
            s1[j] = f2bf(fL[i][1][j] + fL[i][3][j]);   // c = lane + 64
        }
        #pragma unroll
        for (int j = 0; j < 4; ++j) {
            const unsigned uv = (unsigned)(unsigned short)s0[j]
                              | ((unsigned)(unsigned short)s1[j] << 16);
            *(unsigned*)&fBt[wq * 4 + j][2 * lane] = uv;   // banks = lane mod 32
        }
        *(short4v*)&fA[lane     ][wq * 4] = s0;
        *(short4v*)&fA[lane + 64][wq * 4] = s1;
    }
    __syncthreads();

    // ---------------- Phase B: q,k = [Wq;Wk] f + bias via MFMA ----------------
    f32x4 acc[4][3];
    #pragma unroll
    for (int mf = 0; mf < 4; ++mf)
        #pragma unroll
        for (int nf = 0; nf < 3; ++nf)
            acc[mf][nf] = (f32x4){0.f, 0.f, 0.f, 0.f};

    #pragma unroll
    for (int kk = 0; kk < 4; ++kk) {
        short8 bfr[3];
        #pragma unroll
        for (int nf = 0; nf < 3; ++nf)
            bfr[nf] = *(const short8*)&fBt[nf * 16 + lrow][kk * 32 + lgrp * 8];
        #pragma unroll
        for (int mf = 0; mf < 4; ++mf)
            #pragma unroll
            for (int nf = 0; nf < 3; ++nf)
                acc[mf][nf] = __builtin_amdgcn_mfma_f32_16x16x32_bf16(
                    afrag[mf][kk], bfr[nf], acc[mf][nf], 0, 0, 0);
    }

    // writeback transposed bf16: q -> qT (w rows 8..39), k -> kT (all, zero OOB)
    if (wid < 2) {
        #pragma unroll
        for (int mf = 0; mf < 4; ++mf)
            #pragma unroll
            for (int nf = 0; nf < 3; ++nf) {
                const int wl = nf * 16 + lrow;
                if (wl >= RR && wl < RR + TW) {
                    short4v s;
                    #pragma unroll
                    for (int reg = 0; reg < 4; ++reg)
                        s[reg] = f2bf(acc[mf][nf][reg] + bias_r[mf][reg]);
                    *(short4v*)&qT[wl - RR][mrow + mf * 16 + lgrp * 4] = s;
                }
            }
    } else {
        #pragma unroll
        for (int mf = 0; mf < 4; ++mf)
            #pragma unroll
            for (int nf = 0; nf < 3; ++nf) {
                const int wl = nf * 16 + lrow;
                const int w  = w0 + wl;
                const bool inb = (w >= 0 && w < WW);
                short4v s;
                #pragma unroll
                for (int reg = 0; reg < 4; ++reg)
                    s[reg] = inb ? f2bf(acc[mf][nf][reg] + bias_r[mf][reg]) : (short)0;
                *(short4v*)&kT[wl][mrow + mf * 16 + lgrp * 4] = s;
            }
    }
    __syncthreads();   // fBt dead from here -> St/Pt may use its space

    // ---------------- Phase C: S^T = (q^T k) / sqrt(C) via MFMA ---------------
    if (wid < 3) {
        const int nf = wid;          // wl' block 0..2
        f32x4 s0 = {0.f,0.f,0.f,0.f}, s1 = {0.f,0.f,0.f,0.f};
        #pragma unroll
        for (int kk = 0; kk < 4; ++kk) {
            const short8 a0 = *(const short8*)&qT[lrow     ][kk * 32 + lgrp * 8];
            const short8 a1 = *(const short8*)&qT[16 + lrow][kk * 32 + lgrp * 8];
            const short8 bb = *(const short8*)&kT[nf * 16 + lrow][kk * 32 + lgrp * 8];
            s0 = __builtin_amdgcn_mfma_f32_16x16x32_bf16(a0, bb, s0, 0, 0, 0);
            s1 = __builtin_amdgcn_mfma_f32_16x16x32_bf16(a1, bb, s1, 0, 0, 0);
        }
        const float isc = 0.08838834764831845f;   // 1/sqrt(128)
        *(f32x4*)&St[nf * 16 + lrow][lgrp * 4]      = s0 * isc;
        *(f32x4*)&St[nf * 16 + lrow][16 + lgrp * 4] = s1 * isc;
    } else {
        // wave 3: zero-fill Pt (32 x 72 shorts = 288 short8 chunks)
        const short8 z = {0,0,0,0,0,0,0,0};
        short* p = &Pt[0][0];
        for (int i = lane; i < (TW * PTP) / 8; i += 64)
            *(short8*)(p + i * 8) = z;
    }
    __syncthreads();

    // ---------------- softmax over 17 taps (parallel: 4 threads/row) ---------
    if (t < TW * 4) {
        const int w = t >> 2, g = t & 3;
        const int nt = (g == 0) ? 5 : 4;          // taps j = g + 4i, plus j=16 for g==0
        float sv[5];
        float mx = -3.0e38f;
        #pragma unroll
        for (int i = 0; i < 5; ++i) {
            if (i < nt) {
                const int j = (i == 4) ? 16 : (g + i * 4);
                sv[i] = St[w + j][w];
                mx = fmaxf(mx, sv[i]);
            }
        }
        mx = fmaxf(mx, __shfl_xor(mx, 1, 4));
        mx = fmaxf(mx, __shfl_xor(mx, 2, 4));
        float sum = 0.f;
        #pragma unroll
        for (int i = 0; i < 5; ++i)
            if (i < nt) { sv[i] = __expf(sv[i] - mx); sum += sv[i]; }
        sum += __shfl_xor(sum, 1, 4);
        sum += __shfl_xor(sum, 2, 4);
        const float inv = 1.f / sum;
        #pragma unroll
        for (int i = 0; i < 5; ++i)
            if (i < nt) {
                const int j = (i == 4) ? 16 : (g + i * 4);
                Pt[w][w + j] = f2bf(sv[i] * inv);
            }
    }
    __syncthreads();

    // ---------------- Phase D: out = f . P^T via MFMA -------------------------
    {
        const int cb = wid * 32;
        f32x4 d00 = {0.f,0.f,0.f,0.f}, d01 = d00, d10 = d00, d11 = d00;
        #pragma unroll
        for (int kk = 0; kk < 2; ++kk) {
            const short8 a0 = *(const short8*)&fA[cb + lrow     ][kk * 32 + lgrp * 8];
            const short8 a1 = *(const short8*)&fA[cb + 16 + lrow][kk * 32 + lgrp * 8];
            const short8 b0 = *(const short8*)&Pt[lrow     ][kk * 32 + lgrp * 8];
            const short8 b1 = *(const short8*)&Pt[16 + lrow][kk * 32 + lgrp * 8];
            d00 = __builtin_amdgcn_mfma_f32_16x16x32_bf16(a0, b0, d00, 0, 0, 0);
            d01 = __builtin_amdgcn_mfma_f32_16x16x32_bf16(a0, b1, d01, 0, 0, 0);
            d10 = __builtin_amdgcn_mfma_f32_16x16x32_bf16(a1, b0, d10, 0, 0, 0);
            d11 = __builtin_amdgcn_mfma_f32_16x16x32_bf16(a1, b1, d11, 0, 0, 0);
        }
        const int wbase = wt * TW;
        #pragma unroll
        for (int reg = 0; reg < 4; ++reg) {
            const int c0 = cb + lgrp * 4 + reg;
            out[base + c0 * (HH * WW)        + wbase + lrow]      = d00[reg];
            out[base + c0 * (HH * WW)        + wbase + 16 + lrow] = d01[reg];
            out[base + (c0 + 16) * (HH * WW) + wbase + lrow]      = d10[reg];
            out[base + (c0 + 16) * (HH * WW) + wbase + 16 + lrow] = d11[reg];
        }
    }
}

extern "C" void kernel_launch(void* const* d_in, const int* in_sizes, int n_in,
                              void* d_out, int out_size, void* d_ws, size_t ws_size,
                              hipStream_t stream) {
    const float* feature  = (const float*)d_in[0];
    const float* position = (const float*)d_in[1];
    const float* Wq = (const float*)d_in[2];
    const float* bq = (const float*)d_in[3];
    const float* Wk = (const float*)d_in[4];
    const float* bk = (const float*)d_in[5];
    float* out = (float*)d_out;

    const dim3 grid(BB * HH * (WW / TW));   // 2048 blocks
    attn1d_fused<<<grid, NTHREADS, 0, stream>>>(feature, position, Wq, bq, Wk, bk, out);
}

// Round 9
// 40.105 us; speedup vs baseline: 1.9403x; 1.5258x over previous
//
#include <hip/hip_runtime.h>
#include <hip/hip_bf16.h>
#include <math.h>

#define BB 4
#define CCH 128     // channels
#define HH 64
#define WW 256
#define RR 8
#define KWIN 17
#define TW 32       // output w-tile per block
#define TWH 48      // TW + 2R (halo)
#define NTHREADS 256
#define PIT 136     // fBt/gT pitch (shorts): 272B rows, 16B-mult, bank-staggered
#define FAP 48      // fA pitch (shorts): 96B rows (cols 48+ never read; D predicated)
#define PTP 48      // Pt pitch (shorts): 96B rows
#define PT_HI 5440  // short offset of Pt rows 16..31 (byte 10880 = fBt row 40)
#define MROWS 144   // M' rows: 128 M + 1 u-row + 15 zero

typedef __attribute__((ext_vector_type(8))) short short8;
typedef __attribute__((ext_vector_type(4))) short short4v;
typedef __attribute__((ext_vector_type(4))) float f32x4;

__device__ __forceinline__ short f2bf(float x) {
    union { __hip_bfloat16 b; short s; } u;
    u.b = __float2bfloat16(x);
    return u.s;
}

// ---- prep: M' bf16 [144][128] = [Wq^T Wk ; (Wk^T bq)^T ; zeros] into d_ws ----
// S = q^T k = f^T (Wq^T Wk) f + (Wk^T bq).f_w' + row-const terms (drop in softmax).
__global__ __launch_bounds__(128)
void prep_kernel(const float* __restrict__ Wq, const float* __restrict__ bq,
                 const float* __restrict__ Wk, short* __restrict__ Mp)
{
    const int r = blockIdx.x;      // 0..143
    const int c = threadIdx.x;     // 0..127
    float acc = 0.f;
    if (r < CCH) {
        #pragma unroll 4
        for (int j = 0; j < CCH; ++j)
            acc = fmaf(Wq[j * CCH + r], Wk[j * CCH + c], acc);
    } else if (r == CCH) {
        #pragma unroll 4
        for (int o = 0; o < CCH; ++o)
            acc = fmaf(bq[o], Wk[o * CCH + c], acc);
    }
    Mp[r * CCH + c] = f2bf(acc);
}

// St embedded in gT region: St row r lives inside the 16-row gT block (r>>4)
// that only wave (r>>4) reads -> write-after-own-read, no cross-wave race.
#define ST_IDX(r) (((r) >> 4) * 1088 + ((r) & 15) * 36)   // float index into gT region

__global__ __launch_bounds__(NTHREADS, 4)
void attn1d_fused(const float* __restrict__ feature,
                  const float* __restrict__ position,
                  const short* __restrict__ Mp,
                  float* __restrict__ out)
{
    // uA: fBt [48][136] (stage->C); Pt overlays fBt rows 0..7 / 40..47 (C-dead)
    // uB: gT [48][136] (B->C); St embedded per-16-row block (C->softmax)
    __shared__ __align__(16) char uA[TWH * PIT * 2];     // 13056
    __shared__ __align__(16) char uB[TWH * PIT * 2];     // 13056
    __shared__ __align__(16) short fA[CCH][FAP];         // 12288  f [c][wl]
    __shared__ float ubias[TWH];                         //   192
                                                         // total 38592 -> 4 blocks/CU
    short (*fBt)[PIT] = (short(*)[PIT])uA;
    short (*gT)[PIT]  = (short(*)[PIT])uB;
    float* Stp        = (float*)uB;
    short* uAs        = (short*)uA;

    const int t    = threadIdx.x;
    const int wid  = t >> 6;
    const int lane = t & 63;
    const int lrow = lane & 15;
    const int lgrp = lane >> 4;

    // XCD-chunked bijective swizzle (2048 % 8 == 0)
    int blk = blockIdx.x;
    blk = (blk & 7) * 256 + (blk >> 3);
    const int wt = blk & 7;
    const int bh = blk >> 3;
    const int h  = bh & (HH - 1);
    const int b  = bh >> 6;
    const int w0 = wt * TW - RR;
    const int base = ((b * CCH) * HH + h) * WW;

    // ---- M-fragments from ws (bf16, direct 16B loads; L2-shared across blocks)
    const int mrow = wid * 32;
    short8 Mf[2][4];            // [mf][kk] rows mrow..mrow+31
    #pragma unroll
    for (int mf = 0; mf < 2; ++mf)
        #pragma unroll
        for (int kk = 0; kk < 4; ++kk)
            Mf[mf][kk] = *(const short8*)(Mp + (mrow + mf * 16 + lrow) * CCH
                                             + kk * 32 + lgrp * 8);
    short8 Mf2[4];              // wave 3 only: rows 128..143 (row 128 = u)
    if (wid == 3) {
        #pragma unroll
        for (int kk = 0; kk < 4; ++kk)
            Mf2[kk] = *(const short8*)(Mp + (CCH + lrow) * CCH + kk * 32 + lgrp * 8);
    }

    // ---------------- Phase A: stage f as fBt (transposed) + fA --------------
    #pragma unroll
    for (int i = 0; i < 6; ++i) {
        const int idx = i * NTHREADS + t;        // 1536 quads
        const int c  = idx / 12;
        const int wq = idx - c * 12;
        const int w  = w0 + wq * 4;              // quad fully in or out (w0 % 4 == 0)
        float4 fv = {0.f, 0.f, 0.f, 0.f};
        if (w >= 0 && w < WW) {
            const int off = base + c * (HH * WW) + w;
            const float4 fa = *(const float4*)(feature + off);
            const float4 pa = *(const float4*)(position + off);
            fv.x = fa.x + pa.x; fv.y = fa.y + pa.y;
            fv.z = fa.z + pa.z; fv.w = fa.w + pa.w;
        }
        short4v s4;
        s4[0] = f2bf(fv.x); s4[1] = f2bf(fv.y); s4[2] = f2bf(fv.z); s4[3] = f2bf(fv.w);
        *(short4v*)&fA[c][wq * 4] = s4;
        fBt[wq * 4 + 0][c] = s4[0];
        fBt[wq * 4 + 1][c] = s4[1];
        fBt[wq * 4 + 2][c] = s4[2];
        fBt[wq * 4 + 3][c] = s4[3];
    }
    __syncthreads();

    // ---------------- Phase B: g = M f via MFMA (all 4 waves, 32 rows each) ---
    {
        f32x4 acc[2][3];
        #pragma unroll
        for (int mf = 0; mf < 2; ++mf)
            #pragma unroll
            for (int nf = 0; nf < 3; ++nf)
                acc[mf][nf] = (f32x4){0.f, 0.f, 0.f, 0.f};
        f32x4 acc2[3];
        #pragma unroll
        for (int nf = 0; nf < 3; ++nf) acc2[nf] = (f32x4){0.f, 0.f, 0.f, 0.f};

        #pragma unroll
        for (int kk = 0; kk < 4; ++kk) {
            short8 bfr[3];
            #pragma unroll
            for (int nf = 0; nf < 3; ++nf)
                bfr[nf] = *(const short8*)&fBt[nf * 16 + lrow][kk * 32 + lgrp * 8];
            #pragma unroll
            for (int mf = 0; mf < 2; ++mf)
                #pragma unroll
                for (int nf = 0; nf < 3; ++nf)
                    acc[mf][nf] = __builtin_amdgcn_mfma_f32_16x16x32_bf16(
                        Mf[mf][kk], bfr[nf], acc[mf][nf], 0, 0, 0);
            if (wid == 3) {
                #pragma unroll
                for (int nf = 0; nf < 3; ++nf)
                    acc2[nf] = __builtin_amdgcn_mfma_f32_16x16x32_bf16(
                        Mf2[kk], bfr[nf], acc2[nf], 0, 0, 0);
            }
        }

        // writeback g^T (bf16): rows wl = nf*16+lrow, cols mrow+mf*16+lgrp*4+reg
        #pragma unroll
        for (int mf = 0; mf < 2; ++mf)
            #pragma unroll
            for (int nf = 0; nf < 3; ++nf) {
                short4v s;
                #pragma unroll
                for (int reg = 0; reg < 4; ++reg)
                    s[reg] = f2bf(acc[mf][nf][reg]);
                *(short4v*)&gT[nf * 16 + lrow][mrow + mf * 16 + lgrp * 4] = s;
            }
        // ubias[wl'] = (u . f_wl') * isc from M' row 128 (m=0 <=> lgrp==0,reg 0)
        if (wid == 3 && lgrp == 0) {
            const float isc = 0.08838834764831845f;
            #pragma unroll
            for (int nf = 0; nf < 3; ++nf)
                ubias[nf * 16 + lrow] = acc2[nf][0] * isc;
        }
    }
    __syncthreads();

    // ---------------- Phase C: S^T = (f^T g) / sqrt(C) via MFMA ---------------
    // waves 0-2: A = fBt rows 8..39 (center w), B = gT own 16-row block.
    // wave 3: zero Pt (lives in fBt rows 0..7 / 40..47 -- not read in C).
    if (wid < 3) {
        const int nf = wid;          // wl' block 0..2
        f32x4 s0 = {0.f,0.f,0.f,0.f}, s1 = {0.f,0.f,0.f,0.f};
        #pragma unroll
        for (int kk = 0; kk < 4; ++kk) {
            const short8 a0 = *(const short8*)&fBt[RR + lrow     ][kk * 32 + lgrp * 8];
            const short8 a1 = *(const short8*)&fBt[RR + 16 + lrow][kk * 32 + lgrp * 8];
            const short8 bb = *(const short8*)&gT[nf * 16 + lrow][kk * 32 + lgrp * 8];
            s0 = __builtin_amdgcn_mfma_f32_16x16x32_bf16(a0, bb, s0, 0, 0, 0);
            s1 = __builtin_amdgcn_mfma_f32_16x16x32_bf16(a1, bb, s1, 0, 0, 0);
        }
        const float isc = 0.08838834764831845f;   // 1/sqrt(128)
        const int sb = ST_IDX(nf * 16 + lrow);    // write inside own gT block
        *(f32x4*)&Stp[sb + lgrp * 4]      = s0 * isc;
        *(f32x4*)&Stp[sb + 16 + lgrp * 4] = s1 * isc;
    } else {
        const short8 z = {0,0,0,0,0,0,0,0};
        #pragma unroll
        for (int i = 0; i < 2; ++i) {
            const int q8 = i * 64 + lane;         // 96 short8 per chunk
            if (q8 < 96) {
                *(short8*)(uAs + q8 * 8) = z;            // Pt rows 0..15
                *(short8*)(uAs + PT_HI + q8 * 8) = z;    // Pt rows 16..31
            }
        }
    }
    __syncthreads();

    // ---------------- softmax over 17 taps (4 threads/row) -------------------
    if (t < TW * 4) {
        const int w = t >> 2, g = t & 3;
        const int nt = (g == 0) ? 5 : 4;          // taps j = g + 4i, plus j=16 for g==0
        const int prow = (w < 16) ? (w * PTP) : (PT_HI + (w - 16) * PTP);
        float sv[5];
        float mx = -3.0e38f;
        #pragma unroll
        for (int i = 0; i < 5; ++i) {
            if (i < nt) {
                const int j = (i == 4) ? 16 : (g + i * 4);
                const int r = w + j;
                sv[i] = Stp[ST_IDX(r) + w] + ubias[r];
                mx = fmaxf(mx, sv[i]);
            }
        }
        mx = fmaxf(mx, __shfl_xor(mx, 1, 4));
        mx = fmaxf(mx, __shfl_xor(mx, 2, 4));
        float sum = 0.f;
        #pragma unroll
        for (int i = 0; i < 5; ++i)
            if (i < nt) { sv[i] = __expf(sv[i] - mx); sum += sv[i]; }
        sum += __shfl_xor(sum, 1, 4);
        sum += __shfl_xor(sum, 2, 4);
        const float inv = 1.f / sum;
        #pragma unroll
        for (int i = 0; i < 5; ++i)
            if (i < nt) {
                const int j = (i == 4) ? 16 : (g + i * 4);
                uAs[prow + w + j] = f2bf(sv[i] * inv);
            }
    }
    __syncthreads();

    // ---------------- Phase D: out = f . P^T via MFMA -------------------------
    // kk=1 & lgrp>=2 -> k-cols 48..63: A-side zero (fA has no such cols).
    {
        const int cb = wid * 32;
        const short8 z = {0,0,0,0,0,0,0,0};
        f32x4 d00 = {0.f,0.f,0.f,0.f}, d01 = d00, d10 = d00, d11 = d00;
        #pragma unroll
        for (int kk = 0; kk < 2; ++kk) {
            const int koff = kk * 32 + lgrp * 8;
            const bool live = (koff < TWH);
            short8 a0 = z, a1 = z, b0 = z, b1 = z;
            if (live) {
                a0 = *(const short8*)&fA[cb + lrow     ][koff];
                a1 = *(const short8*)&fA[cb + 16 + lrow][koff];
                b0 = *(const short8*)(uAs + lrow * PTP + koff);           // Pt rows 0..15
                b1 = *(const short8*)(uAs + PT_HI + lrow * PTP + koff);   // Pt rows 16..31
            }
            d00 = __builtin_amdgcn_mfma_f32_16x16x32_bf16(a0, b0, d00, 0, 0, 0);
            d01 = __builtin_amdgcn_mfma_f32_16x16x32_bf16(a0, b1, d01, 0, 0, 0);
            d10 = __builtin_amdgcn_mfma_f32_16x16x32_bf16(a1, b0, d10, 0, 0, 0);
            d11 = __builtin_amdgcn_mfma_f32_16x16x32_bf16(a1, b1, d11, 0, 0, 0);
        }
        const int wbase = wt * TW;
        #pragma unroll
        for (int reg = 0; reg < 4; ++reg) {
            const int c0 = cb + lgrp * 4 + reg;
            out[base + c0 * (HH * WW)        + wbase + lrow]      = d00[reg];
            out[base + c0 * (HH * WW)        + wbase + 16 + lrow] = d01[reg];
            out[base + (c0 + 16) * (HH * WW) + wbase + lrow]      = d10[reg];
            out[base + (c0 + 16) * (HH * WW) + wbase + 16 + lrow] = d11[reg];
        }
    }
}

extern "C" void kernel_launch(void* const* d_in, const int* in_sizes, int n_in,
                              void* d_out, int out_size, void* d_ws, size_t ws_size,
                              hipStream_t stream) {
    const float* feature  = (const float*)d_in[0];
    const float* position = (const float*)d_in[1];
    const float* Wq = (const float*)d_in[2];
    const float* bq = (const float*)d_in[3];
    const float* Wk = (const float*)d_in[4];
    const float* bk = (const float*)d_in[5];   // only affects row-const softmax terms
    (void)bk;
    float* out = (float*)d_out;
    short* Mp  = (short*)d_ws;                 // 144x128 bf16 = 36864 B

    prep_kernel<<<MROWS, 128, 0, stream>>>(Wq, bq, Wk, Mp);
    const dim3 grid(BB * HH * (WW / TW));      // 2048 blocks, 4/CU -> 2 exact rounds
    attn1d_fused<<<grid, NTHREADS, 0, stream>>>(feature, position, Mp, out);
}